// Round 5
// baseline (284.310 us; speedup 1.0000x reference)
//
#include <hip/hip_runtime.h>
#include <hip/hip_bf16.h>

#define NN 65536
#define EE 655360
#define GG 256
#define EGOC 64
#define SS (GG*EGOC)
#define HH 128
#define PP 64
#define OUTD 10
#define LLAYERS 3
#define PADW 40   // padded LDS row stride in halfwords
#define EPB1 5120 // edges per bucket1 block
#define BCAP 4096 // per-bucket capacity

typedef __attribute__((ext_vector_type(8))) short short8_t;   // 8 bf16 = 4 VGPR
typedef __attribute__((ext_vector_type(4))) float f32x4_t;

__device__ __forceinline__ unsigned short f2bf(float f){
  unsigned u = __float_as_uint(f);
  unsigned r = (u + 0x7fffu + ((u >> 16) & 1u)) >> 16;   // RNE
  return (unsigned short)r;
}
__device__ __forceinline__ float bflo(unsigned v){ return __uint_as_float(v << 16); }
__device__ __forceinline__ float bfhi(unsigned v){ return __uint_as_float(v & 0xffff0000u); }

// ---------- x (fp32) -> bf16 ----------
__global__ __launch_bounds__(256) void x2bf(const float* __restrict__ x,
                                            unsigned short* __restrict__ xb){
  const size_t i = ((size_t)blockIdx.x * 256 + threadIdx.x) * 8;
  float4 a = *(const float4*)(x + i);
  float4 b = *(const float4*)(x + i + 4);
  uint4 o;
  o.x = f2bf(a.x) | ((unsigned)f2bf(a.y) << 16);
  o.y = f2bf(a.z) | ((unsigned)f2bf(a.w) << 16);
  o.z = f2bf(b.x) | ((unsigned)f2bf(b.y) << 16);
  o.w = f2bf(b.z) | ((unsigned)f2bf(b.w) << 16);
  *(uint4*)(xb + i) = o;
}

// ---------- transpose weights to [layer][rel|root][n][k] bf16 ----------
__global__ __launch_bounds__(128) void wt_k(const float* __restrict__ w_rel,
    const float* __restrict__ w_root, unsigned short* __restrict__ wt){
  const int mi = blockIdx.x >> 7;       // 0..5 : layer*2 + (0=rel,1=root)
  const int n  = blockIdx.x & 127;
  const int k  = threadIdx.x;
  const float* src = (mi & 1) ? w_root : w_rel;
  const int l = mi >> 1;
  float v = src[(size_t)l * 16384 + (size_t)k * 128 + n];
  wt[((size_t)mi << 14) + ((size_t)n << 7) + k] = f2bf(v);
}

// ---------- bucket pass 1: multisplit edges by dst>>8 ----------
__global__ __launch_bounds__(256) void bucket1(const int* __restrict__ src,
    const int* __restrict__ dst, int* __restrict__ bucket_cursor,
    unsigned* __restrict__ bdata){
  __shared__ int hist[256], lbase[256], cur[256], rbase[256];
  __shared__ unsigned staged[EPB1];
  const int t = threadIdx.x;
  const int e0 = blockIdx.x * EPB1;
  hist[t] = 0;
  __syncthreads();
  #pragma unroll
  for (int k = 0; k < EPB1/256; ++k){
    int d = dst[e0 + t + k*256];
    atomicAdd(&hist[d >> 8], 1);
  }
  __syncthreads();
  const int cnt = hist[t];
  int val = cnt;
  for (int off = 1; off < 256; off <<= 1){
    int y = (t >= off) ? hist[t - off] : 0;
    __syncthreads();
    val += y;
    hist[t] = val;
    __syncthreads();
  }
  const int excl = val - cnt;
  lbase[t] = excl;
  cur[t] = excl;
  rbase[t] = atomicAdd(&bucket_cursor[t], cnt);
  __syncthreads();
  #pragma unroll
  for (int k = 0; k < EPB1/256; ++k){
    int i = e0 + t + k*256;
    int d = dst[i];
    int s = src[i];
    int b = d >> 8;
    int p = atomicAdd(&cur[b], 1);
    staged[p] = (unsigned)s | ((unsigned)(d & 255) << 16) | ((unsigned)b << 24);
  }
  __syncthreads();
  #pragma unroll
  for (int k = 0; k < EPB1/256; ++k){
    int i = t + k*256;
    unsigned w = staged[i];
    int b = w >> 24;
    bdata[b * BCAP + rbase[b] + (i - lbase[b])] = w;
  }
}

// ---------- bucket pass 2: per-bucket CSR finalize ----------
__global__ __launch_bounds__(256) void bucket2(const unsigned* __restrict__ bdata,
    const int* __restrict__ bucket_cursor, int* __restrict__ rowptr,
    int* __restrict__ csr){
  __shared__ int hist[256], cur[256], red[256];
  const int t = threadIdx.x;
  const int b = blockIdx.x;
  red[t] = (t < b) ? bucket_cursor[t] : 0;
  hist[t] = 0;
  __syncthreads();
  for (int off = 128; off > 0; off >>= 1){
    if (t < off) red[t] += red[t + off];
    __syncthreads();
  }
  const int base = red[0];
  const int cnt = bucket_cursor[b];
  const unsigned* bd = bdata + (size_t)b * BCAP;
  for (int i = t; i < cnt; i += 256)
    atomicAdd(&hist[(bd[i] >> 16) & 255], 1);
  __syncthreads();
  const int c = hist[t];
  int val = c;
  for (int off = 1; off < 256; off <<= 1){
    int y = (t >= off) ? hist[t - off] : 0;
    __syncthreads();
    val += y;
    hist[t] = val;
    __syncthreads();
  }
  const int excl = val - c;
  cur[t] = excl;
  rowptr[(b << 8) + t] = base + excl;
  if (b == 255 && t == 255) rowptr[NN] = EE;
  __syncthreads();
  for (int i = t; i < cnt; i += 256){
    unsigned w = bd[i];
    int dl = (w >> 16) & 255;
    int p = atomicAdd(&cur[dl], 1);
    csr[base + p] = (int)(w & 0xFFFFu);
  }
}

// ---------- fused gather + MFMA conv (one 128-node tile per block) ----------
// Phase A: aggregate neighbor rows into LDS (4 k-chunks).
// Phase B: relu([agg|h] @ [wrel;wroot] + b); last layer pools into pooled128.
__global__ __launch_bounds__(512, 4) void agg_conv(
    const unsigned* __restrict__ hin_u,      // gather source, bf16 pairs
    const int* __restrict__ rowptr, const int* __restrict__ csr,
    const unsigned short* __restrict__ wt,   // [2][128n][128k]: rel then root
    const float* __restrict__ bias,
    unsigned short* __restrict__ out,        // bf16 h out (layers 0,1)
    float* __restrict__ pooled128, const int last){
  __shared__ unsigned short aggL[4][128*PADW];   // 40 KB
  __shared__ unsigned short As[2][128*PADW];     // 20 KB
  __shared__ unsigned short Ws[2][128*PADW];     // 20 KB
  const int tid = threadIdx.x;
  const int row0 = blockIdx.x << 7;
  const int lane = tid & 63, wid = tid >> 6;
  const int half = lane >> 5, c = lane & 31;
  const unsigned short* Ah = (const unsigned short*)hin_u;

  // ---- Phase A: gather 128 rows, 16 nodes/wave, 4-node round robin ----
  {
    const int nb = row0 + (wid << 4);
    for (int g = 0; g < 4; ++g){
      const int n0 = nb + (g << 2);
      int jj[4], ee[4];
      #pragma unroll
      for (int t = 0; t < 4; ++t){ jj[t] = rowptr[n0 + t]; ee[t] = rowptr[n0 + t + 1]; }
      float ac[4][4];
      #pragma unroll
      for (int t = 0; t < 4; ++t){ ac[t][0]=ac[t][1]=ac[t][2]=ac[t][3]=0.f; }
      int s_[4][2]; bool v_[4][2];
      #pragma unroll
      for (int t = 0; t < 4; ++t){
        int e0 = jj[t] + half, e1 = jj[t] + 2 + half;
        v_[t][0] = e0 < ee[t]; v_[t][1] = e1 < ee[t];
        s_[t][0] = csr[v_[t][0] ? e0 : 0];
        s_[t][1] = csr[v_[t][1] ? e1 : 0];
      }
      bool live = (jj[0]<ee[0])||(jj[1]<ee[1])||(jj[2]<ee[2])||(jj[3]<ee[3]);
      while (live){
        uint2 w_[4][2];
        #pragma unroll
        for (int t = 0; t < 4; ++t){
          w_[t][0] = *(const uint2*)(hin_u + ((size_t)s_[t][0] << 6) + (c << 1));
          w_[t][1] = *(const uint2*)(hin_u + ((size_t)s_[t][1] << 6) + (c << 1));
        }
        #pragma unroll
        for (int t = 0; t < 4; ++t) jj[t] += 4;
        live = (jj[0]<ee[0])||(jj[1]<ee[1])||(jj[2]<ee[2])||(jj[3]<ee[3]);
        int sn[4][2]; bool vn[4][2];
        if (live){
          #pragma unroll
          for (int t = 0; t < 4; ++t){
            int e0 = jj[t] + half, e1 = jj[t] + 2 + half;
            vn[t][0] = e0 < ee[t]; vn[t][1] = e1 < ee[t];
            sn[t][0] = csr[vn[t][0] ? e0 : 0];
            sn[t][1] = csr[vn[t][1] ? e1 : 0];
          }
        }
        #pragma unroll
        for (int t = 0; t < 4; ++t){
          if (v_[t][0]){ ac[t][0]+=bflo(w_[t][0].x); ac[t][1]+=bfhi(w_[t][0].x);
                         ac[t][2]+=bflo(w_[t][0].y); ac[t][3]+=bfhi(w_[t][0].y); }
          if (v_[t][1]){ ac[t][0]+=bflo(w_[t][1].x); ac[t][1]+=bfhi(w_[t][1].x);
                         ac[t][2]+=bflo(w_[t][1].y); ac[t][3]+=bfhi(w_[t][1].y); }
        }
        if (live){
          #pragma unroll
          for (int t = 0; t < 4; ++t){
            v_[t][0]=vn[t][0]; v_[t][1]=vn[t][1];
            s_[t][0]=sn[t][0]; s_[t][1]=sn[t][1];
          }
        }
      }
      #pragma unroll
      for (int t = 0; t < 4; ++t){
        #pragma unroll
        for (int r = 0; r < 4; ++r) ac[t][r] += __shfl_xor(ac[t][r], 32, 64);
      }
      if (lane < 32){
        #pragma unroll
        for (int t = 0; t < 4; ++t){
          const int row = (wid << 4) + (g << 2) + t;
          uint2 pk;
          pk.x = (unsigned)f2bf(ac[t][0]) | ((unsigned)f2bf(ac[t][1]) << 16);
          pk.y = (unsigned)f2bf(ac[t][2]) | ((unsigned)f2bf(ac[t][3]) << 16);
          *(uint2*)&aggL[c >> 3][row * PADW + ((c & 7) << 2)] = pk;
        }
      }
    }
  }

  // ---- Phase B: MFMA over 8 k-chunks (0-3: rel from aggL, 4-7: root staged) ----
  const int r0 = tid >> 2;            // staging row 0..127
  const int s8 = (tid & 3) << 3;      // staging k-slot (halfwords)
  const int wm = (wid >> 2) << 6;     // 0 / 64
  const int wn = (wid & 3) << 5;      // 0 / 32 / 64 / 96
  const int fr = lane & 15;
  const int fs = (lane >> 4) << 3;

  f32x4_t acc[4][2];
  #pragma unroll
  for (int i = 0; i < 4; ++i)
    #pragma unroll
    for (int j = 0; j < 2; ++j) acc[i][j] = (f32x4_t){0.f,0.f,0.f,0.f};

  {
    uint4 gw0 = *(const uint4*)(wt + (size_t)r0 * 128 + s8);
    *(uint4*)&Ws[0][r0 * PADW + s8] = gw0;
  }
  __syncthreads();   // aggL + Ws[0] ready

  uint4 ga, gw;
  for (int ch = 0; ch < 8; ++ch){
    const int b = ch & 1;
    if (ch < 7){
      const int cn = ch + 1;
      const unsigned short* Wp = (cn < 4) ? wt : (wt + 16384);
      const int k0 = (cn & 3) << 5;
      gw = *(const uint4*)(Wp + (size_t)r0 * 128 + k0 + s8);
      if (cn >= 4) ga = *(const uint4*)(Ah + (size_t)(row0 + r0) * 128 + k0 + s8);
    }
    const unsigned short* Ab = (ch < 4) ? &aggL[ch][0] : &As[b][0];
    short8_t af[4], wf[2];
    #pragma unroll
    for (int i = 0; i < 4; ++i)
      af[i] = *(const short8_t*)&Ab[(wm + i*16 + fr) * PADW + fs];
    #pragma unroll
    for (int j = 0; j < 2; ++j)
      wf[j] = *(const short8_t*)&Ws[b][(wn + j*16 + fr) * PADW + fs];
    #pragma unroll
    for (int j = 0; j < 2; ++j)
      #pragma unroll
      for (int i = 0; i < 4; ++i)
        acc[i][j] = __builtin_amdgcn_mfma_f32_16x16x32_bf16(wf[j], af[i], acc[i][j], 0, 0, 0);
    if (ch < 7){
      const int cn = ch + 1;
      *(uint4*)&Ws[b ^ 1][r0 * PADW + s8] = gw;
      if (cn >= 4) *(uint4*)&As[b ^ 1][r0 * PADW + s8] = ga;
      __syncthreads();
    }
  }

  // ---- epilogue ----
  if (!last){
    #pragma unroll
    for (int j = 0; j < 2; ++j){
      const int n0 = wn + j*16 + ((lane >> 4) << 2);
      const float4 b4 = *(const float4*)(bias + n0);
      #pragma unroll
      for (int i = 0; i < 4; ++i){
        const int m = row0 + wm + i*16 + fr;
        float v0 = fmaxf(acc[i][j][0] + b4.x, 0.f);
        float v1 = fmaxf(acc[i][j][1] + b4.y, 0.f);
        float v2 = fmaxf(acc[i][j][2] + b4.z, 0.f);
        float v3 = fmaxf(acc[i][j][3] + b4.w, 0.f);
        uint2 pk;
        pk.x = (unsigned)f2bf(v0) | ((unsigned)f2bf(v1) << 16);
        pk.y = (unsigned)f2bf(v2) | ((unsigned)f2bf(v3) << 16);
        *(uint2*)(out + (size_t)m * 128 + n0) = pk;
      }
    }
  } else {
    #pragma unroll
    for (int j = 0; j < 2; ++j){
      const int n0 = wn + j*16 + ((lane >> 4) << 2);
      const float4 b4 = *(const float4*)(bias + n0);
      #pragma unroll
      for (int i = 0; i < 4; ++i){
        const int m = row0 + wm + i*16 + fr;
        const int seg = ((m >> 8) << 6) | (m & 63);
        float* pp = pooled128 + (size_t)seg * 128 + n0;
        atomicAdd(pp + 0, fmaxf(acc[i][j][0] + b4.x, 0.f));
        atomicAdd(pp + 1, fmaxf(acc[i][j][1] + b4.y, 0.f));
        atomicAdd(pp + 2, fmaxf(acc[i][j][2] + b4.z, 0.f));
        atomicAdd(pp + 3, fmaxf(acc[i][j][3] + b4.w, 0.f));
      }
    }
  }
}

// ---------- pooled[s] = pooled128[s] @ down_w ----------
__global__ __launch_bounds__(256) void proj64(const float* __restrict__ p128,
    const float* __restrict__ down_w, float* __restrict__ pooled){
  __shared__ float wds[128 * 64];   // [k][c], 32 KB
  __shared__ float hs[4][128];
  const int tid = threadIdx.x;
  for (int i = tid; i < 128 * 64 / 4; i += 256)
    ((float4*)wds)[i] = ((const float4*)down_w)[i];
  __syncthreads();
  const int wid = tid >> 6, lane = tid & 63;
  for (int it = 0; it < 4; ++it){
    const int s = (blockIdx.x << 4) + (it << 2) + wid;
    float2 v = *(const float2*)(p128 + (size_t)s * 128 + (lane << 1));
    hs[wid][(lane << 1) + 0] = v.x;
    hs[wid][(lane << 1) + 1] = v.y;
    float a0 = 0.f, a1 = 0.f, a2 = 0.f, a3 = 0.f;
    #pragma unroll
    for (int k = 0; k < 128; k += 4){
      a0 = fmaf(hs[wid][k + 0], wds[(k + 0) * 64 + lane], a0);
      a1 = fmaf(hs[wid][k + 1], wds[(k + 1) * 64 + lane], a1);
      a2 = fmaf(hs[wid][k + 2], wds[(k + 2) * 64 + lane], a2);
      a3 = fmaf(hs[wid][k + 3], wds[(k + 3) * 64 + lane], a3);
    }
    pooled[(size_t)s * 64 + lane] = (a0 + a1) + (a2 + a3);
  }
}

// ---------- per-graph softmax aggregation ----------
__global__ __launch_bounds__(256) void graph_softmax(const float* __restrict__ pooled,
    float* __restrict__ gout){
  __shared__ float ps[4096];
  __shared__ float r1[4][64], r2[4][64];
  const int tid = threadIdx.x;
  const float* P = pooled + (size_t)blockIdx.x * 4096;
  for (int i = tid; i < 1024; i += 256)
    ((float4*)ps)[i] = ((const float4*)P)[i];
  __syncthreads();
  const int wid = tid >> 6, lane = tid & 63;
  float m = -3.4e38f;
  #pragma unroll
  for (int r = 0; r < 16; ++r) m = fmaxf(m, ps[((wid << 4) + r) * 64 + lane]);
  r1[wid][lane] = m;
  __syncthreads();
  m = fmaxf(fmaxf(r1[0][lane], r1[1][lane]), fmaxf(r1[2][lane], r1[3][lane]));
  __syncthreads();
  float se = 0.f, sn = 0.f;
  #pragma unroll
  for (int r = 0; r < 16; ++r){
    float p = ps[((wid << 4) + r) * 64 + lane];
    float ev = expf(p - m);
    se += ev; sn += ev * p;
  }
  r1[wid][lane] = se; r2[wid][lane] = sn;
  __syncthreads();
  if (wid == 0){
    float d = (r1[0][lane] + r1[1][lane]) + (r1[2][lane] + r1[3][lane]);
    float n = (r2[0][lane] + r2[1][lane]) + (r2[2][lane] + r2[3][lane]);
    gout[(size_t)blockIdx.x * 64 + lane] = n / d;
  }
}

// ---------- MLP ----------
__global__ __launch_bounds__(256) void mlp_kernel(const float* __restrict__ gmat,
    const float* __restrict__ w1, const float* __restrict__ b1,
    const float* __restrict__ gamma, const float* __restrict__ beta,
    const float* __restrict__ w2, const float* __restrict__ b2,
    float* __restrict__ out){
  const int r = threadIdx.x;
  float z[20];
  #pragma unroll
  for (int j = 0; j < 20; ++j) z[j] = b1[j];
  for (int k = 0; k < 64; ++k){
    float gv = gmat[r*64 + k];
    #pragma unroll
    for (int j = 0; j < 20; ++j) z[j] = fmaf(gv, w1[k*20 + j], z[j]);
  }
  __shared__ float red1[4][20], red2[4][20];
  __shared__ float mu[20], istd[20];
  const int lane = r & 63, wid = r >> 6;
  #pragma unroll
  for (int j = 0; j < 20; ++j){
    float a = z[j], b = z[j]*z[j];
    #pragma unroll
    for (int off = 32; off > 0; off >>= 1){
      a += __shfl_xor(a, off, 64);
      b += __shfl_xor(b, off, 64);
    }
    if (lane == 0){ red1[wid][j] = a; red2[wid][j] = b; }
  }
  __syncthreads();
  if (r < 20){
    float m = red1[0][r] + red1[1][r] + red1[2][r] + red1[3][r];
    float q = red2[0][r] + red2[1][r] + red2[2][r] + red2[3][r];
    m *= (1.f/256.f); q *= (1.f/256.f);
    float var = q - m*m;
    mu[r] = m;
    istd[r] = 1.f / sqrtf(var + 1e-5f);
  }
  __syncthreads();
  float o[10];
  #pragma unroll
  for (int jo = 0; jo < 10; ++jo) o[jo] = b2[jo];
  #pragma unroll
  for (int j = 0; j < 20; ++j){
    float zn = (z[j] - mu[j]) * istd[j] * gamma[j] + beta[j];
    zn = fmaxf(zn, 0.f);
    #pragma unroll
    for (int jo = 0; jo < 10; ++jo) o[jo] = fmaf(zn, w2[j*10 + jo], o[jo]);
  }
  #pragma unroll
  for (int jo = 0; jo < 10; ++jo) out[r*10 + jo] = o[jo];
}

// ---------- launch ----------
extern "C" void kernel_launch(void* const* d_in, const int* in_sizes, int n_in,
                              void* d_out, int out_size, void* d_ws, size_t ws_size,
                              hipStream_t stream){
  const float* x      = (const float*)d_in[0];
  const int*   eidx   = (const int*)d_in[1];
  const float* w_root = (const float*)d_in[4];
  const float* w_rel  = (const float*)d_in[5];
  const float* b_conv = (const float*)d_in[6];
  const float* down_w = (const float*)d_in[7];
  const float* w1     = (const float*)d_in[8];
  const float* b1     = (const float*)d_in[9];
  const float* gamma  = (const float*)d_in[10];
  const float* beta   = (const float*)d_in[11];
  const float* w2     = (const float*)d_in[12];
  const float* b2     = (const float*)d_in[13];
  const int* src = eidx;
  const int* dst = eidx + EE;

  char* wsp = (char*)d_ws;
  size_t off = 0;
  auto alloc = [&](size_t bytes)->char*{
    char* p = wsp + off;
    off += (bytes + 255) & ~(size_t)255;
    return p;
  };
  unsigned short* hA   = (unsigned short*)alloc((size_t)NN*HH*2);
  unsigned short* hB   = (unsigned short*)alloc((size_t)NN*HH*2);
  unsigned short* wtb  = (unsigned short*)alloc((size_t)6*128*128*2);
  float*    p128   = (float*)   alloc((size_t)SS*HH*4);
  float*    pooled = (float*)   alloc((size_t)SS*PP*4);
  int*      rowptr = (int*)     alloc((size_t)(NN+1)*4);
  int*      csr    = (int*)     alloc((size_t)EE*4);
  unsigned* bdata  = (unsigned*)alloc((size_t)256*BCAP*4);
  int*      bcur   = (int*)     alloc((size_t)256*4);
  float*    gout   = (float*)   alloc((size_t)GG*PP*4);

  hipMemsetAsync(bcur, 0, 256*4, stream);
  hipMemsetAsync(p128, 0, (size_t)SS*HH*4, stream);

  x2bf<<<NN*HH/8/256, 256, 0, stream>>>(x, hA);
  wt_k<<<6*128, 128, 0, stream>>>(w_rel, w_root, wtb);
  bucket1<<<EE/EPB1, 256, 0, stream>>>(src, dst, bcur, bdata);
  bucket2<<<256, 256, 0, stream>>>(bdata, bcur, rowptr, csr);

  agg_conv<<<NN/128, 512, 0, stream>>>((const unsigned*)hA, rowptr, csr,
      wtb + (size_t)0*32768, b_conv + 0*HH, hB, p128, 0);
  agg_conv<<<NN/128, 512, 0, stream>>>((const unsigned*)hB, rowptr, csr,
      wtb + (size_t)1*32768, b_conv + 1*HH, hA, p128, 0);
  agg_conv<<<NN/128, 512, 0, stream>>>((const unsigned*)hA, rowptr, csr,
      wtb + (size_t)2*32768, b_conv + 2*HH, hB, p128, 1);

  proj64<<<SS/16, 256, 0, stream>>>(p128, down_w, pooled);
  graph_softmax<<<GG, 256, 0, stream>>>(pooled, gout);
  mlp_kernel<<<1, 256, 0, stream>>>(gout, w1, b1, gamma, beta, w2, b2, (float*)d_out);
}

// Round 6
// 218.155 us; speedup vs baseline: 1.3032x; 1.3032x over previous
//
#include <hip/hip_runtime.h>
#include <hip/hip_bf16.h>

#define NN 65536
#define EE 655360
#define GG 256
#define EGOC 64
#define SS (GG*EGOC)
#define HH 128
#define PP 64
#define OUTD 10
#define LLAYERS 3
#define PADW 40   // padded LDS row stride in halfwords
#define EPB1 5120 // edges per bucket1 block
#define BCAP 4096 // per-bucket capacity

typedef __attribute__((ext_vector_type(8))) short short8_t;   // 8 bf16 = 4 VGPR
typedef __attribute__((ext_vector_type(4))) float f32x4_t;

__device__ __forceinline__ unsigned short f2bf(float f){
  unsigned u = __float_as_uint(f);
  unsigned r = (u + 0x7fffu + ((u >> 16) & 1u)) >> 16;   // RNE
  return (unsigned short)r;
}
__device__ __forceinline__ float bflo(unsigned v){ return __uint_as_float(v << 16); }
__device__ __forceinline__ float bfhi(unsigned v){ return __uint_as_float(v & 0xffff0000u); }

// ---------- x (fp32) -> bf16 ----------
__global__ __launch_bounds__(256) void x2bf(const float* __restrict__ x,
                                            unsigned short* __restrict__ xb){
  const size_t i = ((size_t)blockIdx.x * 256 + threadIdx.x) * 8;
  float4 a = *(const float4*)(x + i);
  float4 b = *(const float4*)(x + i + 4);
  uint4 o;
  o.x = f2bf(a.x) | ((unsigned)f2bf(a.y) << 16);
  o.y = f2bf(a.z) | ((unsigned)f2bf(a.w) << 16);
  o.z = f2bf(b.x) | ((unsigned)f2bf(b.y) << 16);
  o.w = f2bf(b.z) | ((unsigned)f2bf(b.w) << 16);
  *(uint4*)(xb + i) = o;
}

// ---------- transpose weights to [layer][rel|root][n][k] bf16 ----------
__global__ __launch_bounds__(128) void wt_k(const float* __restrict__ w_rel,
    const float* __restrict__ w_root, unsigned short* __restrict__ wt){
  const int mi = blockIdx.x >> 7;       // 0..5 : layer*2 + (0=rel,1=root)
  const int n  = blockIdx.x & 127;
  const int k  = threadIdx.x;
  const float* src = (mi & 1) ? w_root : w_rel;
  const int l = mi >> 1;
  float v = src[(size_t)l * 16384 + (size_t)k * 128 + n];
  wt[((size_t)mi << 14) + ((size_t)n << 7) + k] = f2bf(v);
}

// ---------- bucket pass 1: multisplit edges by dst>>8 ----------
__global__ __launch_bounds__(256) void bucket1(const int* __restrict__ src,
    const int* __restrict__ dst, int* __restrict__ bucket_cursor,
    unsigned* __restrict__ bdata){
  __shared__ int hist[256], lbase[256], cur[256], rbase[256];
  __shared__ unsigned staged[EPB1];
  const int t = threadIdx.x;
  const int e0 = blockIdx.x * EPB1;
  hist[t] = 0;
  __syncthreads();
  #pragma unroll
  for (int k = 0; k < EPB1/256; ++k){
    int d = dst[e0 + t + k*256];
    atomicAdd(&hist[d >> 8], 1);
  }
  __syncthreads();
  const int cnt = hist[t];
  int val = cnt;
  for (int off = 1; off < 256; off <<= 1){
    int y = (t >= off) ? hist[t - off] : 0;
    __syncthreads();
    val += y;
    hist[t] = val;
    __syncthreads();
  }
  const int excl = val - cnt;
  lbase[t] = excl;
  cur[t] = excl;
  rbase[t] = atomicAdd(&bucket_cursor[t], cnt);
  __syncthreads();
  #pragma unroll
  for (int k = 0; k < EPB1/256; ++k){
    int i = e0 + t + k*256;
    int d = dst[i];
    int s = src[i];
    int b = d >> 8;
    int p = atomicAdd(&cur[b], 1);
    staged[p] = (unsigned)s | ((unsigned)(d & 255) << 16) | ((unsigned)b << 24);
  }
  __syncthreads();
  #pragma unroll
  for (int k = 0; k < EPB1/256; ++k){
    int i = t + k*256;
    unsigned w = staged[i];
    int b = w >> 24;
    bdata[b * BCAP + rbase[b] + (i - lbase[b])] = w;
  }
}

// ---------- bucket pass 2: per-bucket CSR finalize ----------
__global__ __launch_bounds__(256) void bucket2(const unsigned* __restrict__ bdata,
    const int* __restrict__ bucket_cursor, int* __restrict__ rowptr,
    int* __restrict__ csr){
  __shared__ int hist[256], cur[256], red[256];
  const int t = threadIdx.x;
  const int b = blockIdx.x;
  red[t] = (t < b) ? bucket_cursor[t] : 0;
  hist[t] = 0;
  __syncthreads();
  for (int off = 128; off > 0; off >>= 1){
    if (t < off) red[t] += red[t + off];
    __syncthreads();
  }
  const int base = red[0];
  const int cnt = bucket_cursor[b];
  const unsigned* bd = bdata + (size_t)b * BCAP;
  for (int i = t; i < cnt; i += 256)
    atomicAdd(&hist[(bd[i] >> 16) & 255], 1);
  __syncthreads();
  const int c = hist[t];
  int val = c;
  for (int off = 1; off < 256; off <<= 1){
    int y = (t >= off) ? hist[t - off] : 0;
    __syncthreads();
    val += y;
    hist[t] = val;
    __syncthreads();
  }
  const int excl = val - c;
  cur[t] = excl;
  rowptr[(b << 8) + t] = base + excl;
  if (b == 255 && t == 255) rowptr[NN] = EE;
  __syncthreads();
  for (int i = t; i < cnt; i += 256){
    unsigned w = bd[i];
    int dl = (w >> 16) & 255;
    int p = atomicAdd(&cur[dl], 1);
    csr[base + p] = (int)(w & 0xFFFFu);
  }
}

// ---------- aggregation on bf16 rows: aggb[i] = sum_{j->i} hb[j] ----------
// uint4 per lane: 16 lanes cover a 256B row; wave covers 4 edges per load,
// 16 edge slots per iteration -> up to 16 edges (4KB) in flight, exec-masked.
__global__ __launch_bounds__(256) void agg_bf(const unsigned* __restrict__ hb,
    const int* __restrict__ rowptr, const int* __restrict__ csr,
    unsigned* __restrict__ aggb){
  const int wid = threadIdx.x >> 6;
  const int lane = threadIdx.x & 63;
  const int node = (blockIdx.x << 2) + wid;
  const int beg = rowptr[node], end = rowptr[node + 1];
  const int sub = lane >> 4;      // edge slot 0..3
  const int c = lane & 15;        // 16 lanes x 16B cover the row
  float a0=0.f,a1=0.f,a2=0.f,a3=0.f,a4=0.f,a5=0.f,a6=0.f,a7=0.f;
  for (int j = beg; j < end; j += 16){
    #pragma unroll
    for (int u = 0; u < 4; ++u){
      const int e = j + (u << 2) + sub;
      if (e < end){
        const int s = csr[e];
        uint4 w = *(const uint4*)(hb + ((size_t)s << 6) + (c << 2));
        a0 += bflo(w.x); a1 += bfhi(w.x);
        a2 += bflo(w.y); a3 += bfhi(w.y);
        a4 += bflo(w.z); a5 += bfhi(w.z);
        a6 += bflo(w.w); a7 += bfhi(w.w);
      }
    }
  }
  a0 += __shfl_xor(a0, 16, 64); a1 += __shfl_xor(a1, 16, 64);
  a2 += __shfl_xor(a2, 16, 64); a3 += __shfl_xor(a3, 16, 64);
  a4 += __shfl_xor(a4, 16, 64); a5 += __shfl_xor(a5, 16, 64);
  a6 += __shfl_xor(a6, 16, 64); a7 += __shfl_xor(a7, 16, 64);
  a0 += __shfl_xor(a0, 32, 64); a1 += __shfl_xor(a1, 32, 64);
  a2 += __shfl_xor(a2, 32, 64); a3 += __shfl_xor(a3, 32, 64);
  a4 += __shfl_xor(a4, 32, 64); a5 += __shfl_xor(a5, 32, 64);
  a6 += __shfl_xor(a6, 32, 64); a7 += __shfl_xor(a7, 32, 64);
  if (lane < 16){
    uint4 o;
    o.x = (unsigned)f2bf(a0) | ((unsigned)f2bf(a1) << 16);
    o.y = (unsigned)f2bf(a2) | ((unsigned)f2bf(a3) << 16);
    o.z = (unsigned)f2bf(a4) | ((unsigned)f2bf(a5) << 16);
    o.w = (unsigned)f2bf(a6) | ((unsigned)f2bf(a7) << 16);
    *(uint4*)(aggb + ((size_t)node << 6) + (c << 2)) = o;
  }
}

// ---------- MFMA conv: out = relu([agg|h] @ [wrel;wroot] + b), bf16 in/out ----------
__global__ __launch_bounds__(256) void conv_mfma(
    const unsigned short* __restrict__ Aagg, const unsigned short* __restrict__ Ah,
    const unsigned short* __restrict__ wt,   // [2][128n][128k] bf16: rel then root
    const float* __restrict__ bias,
    unsigned short* __restrict__ out){
  __shared__ unsigned short As[2][128 * PADW];
  __shared__ unsigned short Ws[2][128 * PADW];
  const int tid = threadIdx.x;
  const int row0 = blockIdx.x << 7;
  const int lane = tid & 63, wid = tid >> 6;
  const int wm64 = (wid >> 1) << 6;      // m half
  const int wn64 = (wid & 1) << 6;       // n half
  const int fr = lane & 15;              // fragment row
  const int fs = (lane >> 4) << 3;       // fragment k-slot (halfwords)
  const int r0 = tid >> 2;               // staging row 0..63
  const int s8 = (tid & 3) << 3;         // staging k-slot (halfwords)

  f32x4_t acc[4][4];
  #pragma unroll
  for (int i = 0; i < 4; ++i)
    #pragma unroll
    for (int j = 0; j < 4; ++j) acc[i][j] = (f32x4_t){0.f,0.f,0.f,0.f};

  uint4 ga0, ga1, gw0, gw1;

#define STAGE_LOAD(c) do{ \
    const unsigned short* Ap = ((c) < 4) ? Aagg : Ah; \
    const unsigned short* Wp = ((c) < 4) ? wt : (wt + 16384); \
    const int k0 = ((c) & 3) << 5; \
    ga0 = *(const uint4*)(Ap + (size_t)(row0 + r0) * 128 + k0 + s8); \
    ga1 = *(const uint4*)(Ap + (size_t)(row0 + 64 + r0) * 128 + k0 + s8); \
    gw0 = *(const uint4*)(Wp + (size_t)r0 * 128 + k0 + s8); \
    gw1 = *(const uint4*)(Wp + (size_t)(64 + r0) * 128 + k0 + s8); } while(0)
#define STAGE_WRITE(b) do{ \
    *(uint4*)&As[b][r0 * PADW + s8] = ga0; \
    *(uint4*)&As[b][(64 + r0) * PADW + s8] = ga1; \
    *(uint4*)&Ws[b][r0 * PADW + s8] = gw0; \
    *(uint4*)&Ws[b][(64 + r0) * PADW + s8] = gw1; } while(0)

  STAGE_LOAD(0);
  STAGE_WRITE(0);
  __syncthreads();

  for (int c = 0; c < 8; ++c){
    const int b = c & 1;
    if (c < 7) STAGE_LOAD(c + 1);

    short8_t af[4], wf[4];
    #pragma unroll
    for (int i = 0; i < 4; ++i)
      af[i] = *(const short8_t*)&As[b][(wm64 + i*16 + fr) * PADW + fs];
    #pragma unroll
    for (int j = 0; j < 4; ++j)
      wf[j] = *(const short8_t*)&Ws[b][(wn64 + j*16 + fr) * PADW + fs];
    #pragma unroll
    for (int j = 0; j < 4; ++j)
      #pragma unroll
      for (int i = 0; i < 4; ++i)
        acc[i][j] = __builtin_amdgcn_mfma_f32_16x16x32_bf16(wf[j], af[i], acc[i][j], 0, 0, 0);

    if (c < 7){
      STAGE_WRITE(b ^ 1);
      __syncthreads();
    }
  }
#undef STAGE_LOAD
#undef STAGE_WRITE

  // D mapping: col(lane&15) = activation row m; row((lane>>4)*4+r) = weight col n
  #pragma unroll
  for (int j = 0; j < 4; ++j){
    const int n0 = wn64 + j*16 + ((lane >> 4) << 2);
    float4 b4 = *(const float4*)(bias + n0);
    #pragma unroll
    for (int i = 0; i < 4; ++i){
      const int m = row0 + wm64 + i*16 + fr;
      float v0 = fmaxf(acc[i][j][0] + b4.x, 0.f);
      float v1 = fmaxf(acc[i][j][1] + b4.y, 0.f);
      float v2 = fmaxf(acc[i][j][2] + b4.z, 0.f);
      float v3 = fmaxf(acc[i][j][3] + b4.w, 0.f);
      uint2 pk;
      pk.x = (unsigned)f2bf(v0) | ((unsigned)f2bf(v1) << 16);
      pk.y = (unsigned)f2bf(v2) | ((unsigned)f2bf(v3) << 16);
      *(uint2*)(out + (size_t)m * 128 + n0) = pk;
    }
  }
}

// ---------- pooled[s] = (sum_{i in seg s} h_i) @ down_w  (h in bf16) ----------
__global__ __launch_bounds__(256) void pool_proj(const unsigned* __restrict__ hb,
    const float* __restrict__ down_w, float* __restrict__ pooled){
  __shared__ float wds[128 * 64];   // [k][c], 32 KB
  __shared__ float hs[4][128];
  const int tid = threadIdx.x;
  for (int i = tid; i < 128 * 64 / 4; i += 256)
    ((float4*)wds)[i] = ((const float4*)down_w)[i];
  __syncthreads();
  const int wid = tid >> 6, lane = tid & 63;
  for (int it = 0; it < 4; ++it){
    const int s = (blockIdx.x << 4) + (it << 2) + wid;
    const int b = s >> 6, e = s & 63;
    const unsigned* hr = hb + (((size_t)(b * 256 + e)) << 6) + lane;
    float ax = 0.f, ay = 0.f;
    #pragma unroll
    for (int q = 0; q < 4; ++q){
      unsigned v = hr[(size_t)q * 64 * 64];
      ax += bflo(v); ay += bfhi(v);
    }
    hs[wid][(lane << 1) + 0] = ax;
    hs[wid][(lane << 1) + 1] = ay;
    float a0 = 0.f, a1 = 0.f, a2 = 0.f, a3 = 0.f;
    #pragma unroll
    for (int k = 0; k < 128; k += 4){
      a0 = fmaf(hs[wid][k + 0], wds[(k + 0) * 64 + lane], a0);
      a1 = fmaf(hs[wid][k + 1], wds[(k + 1) * 64 + lane], a1);
      a2 = fmaf(hs[wid][k + 2], wds[(k + 2) * 64 + lane], a2);
      a3 = fmaf(hs[wid][k + 3], wds[(k + 3) * 64 + lane], a3);
    }
    pooled[(size_t)s * 64 + lane] = (a0 + a1) + (a2 + a3);
  }
}

// ---------- per-graph softmax aggregation ----------
__global__ __launch_bounds__(256) void graph_softmax(const float* __restrict__ pooled,
    float* __restrict__ gout){
  __shared__ float ps[4096];
  __shared__ float r1[4][64], r2[4][64];
  const int tid = threadIdx.x;
  const float* P = pooled + (size_t)blockIdx.x * 4096;
  for (int i = tid; i < 1024; i += 256)
    ((float4*)ps)[i] = ((const float4*)P)[i];
  __syncthreads();
  const int wid = tid >> 6, lane = tid & 63;
  float m = -3.4e38f;
  #pragma unroll
  for (int r = 0; r < 16; ++r) m = fmaxf(m, ps[((wid << 4) + r) * 64 + lane]);
  r1[wid][lane] = m;
  __syncthreads();
  m = fmaxf(fmaxf(r1[0][lane], r1[1][lane]), fmaxf(r1[2][lane], r1[3][lane]));
  __syncthreads();
  float se = 0.f, sn = 0.f;
  #pragma unroll
  for (int r = 0; r < 16; ++r){
    float p = ps[((wid << 4) + r) * 64 + lane];
    float ev = expf(p - m);
    se += ev; sn += ev * p;
  }
  r1[wid][lane] = se; r2[wid][lane] = sn;
  __syncthreads();
  if (wid == 0){
    float d = (r1[0][lane] + r1[1][lane]) + (r1[2][lane] + r1[3][lane]);
    float n = (r2[0][lane] + r2[1][lane]) + (r2[2][lane] + r2[3][lane]);
    gout[(size_t)blockIdx.x * 64 + lane] = n / d;
  }
}

// ---------- MLP ----------
__global__ __launch_bounds__(256) void mlp_kernel(const float* __restrict__ gmat,
    const float* __restrict__ w1, const float* __restrict__ b1,
    const float* __restrict__ gamma, const float* __restrict__ beta,
    const float* __restrict__ w2, const float* __restrict__ b2,
    float* __restrict__ out){
  const int r = threadIdx.x;
  float z[20];
  #pragma unroll
  for (int j = 0; j < 20; ++j) z[j] = b1[j];
  for (int k = 0; k < 64; ++k){
    float gv = gmat[r*64 + k];
    #pragma unroll
    for (int j = 0; j < 20; ++j) z[j] = fmaf(gv, w1[k*20 + j], z[j]);
  }
  __shared__ float red1[4][20], red2[4][20];
  __shared__ float mu[20], istd[20];
  const int lane = r & 63, wid = r >> 6;
  #pragma unroll
  for (int j = 0; j < 20; ++j){
    float a = z[j], b = z[j]*z[j];
    #pragma unroll
    for (int off = 32; off > 0; off >>= 1){
      a += __shfl_xor(a, off, 64);
      b += __shfl_xor(b, off, 64);
    }
    if (lane == 0){ red1[wid][j] = a; red2[wid][j] = b; }
  }
  __syncthreads();
  if (r < 20){
    float m = red1[0][r] + red1[1][r] + red1[2][r] + red1[3][r];
    float q = red2[0][r] + red2[1][r] + red2[2][r] + red2[3][r];
    m *= (1.f/256.f); q *= (1.f/256.f);
    float var = q - m*m;
    mu[r] = m;
    istd[r] = 1.f / sqrtf(var + 1e-5f);
  }
  __syncthreads();
  float o[10];
  #pragma unroll
  for (int jo = 0; jo < 10; ++jo) o[jo] = b2[jo];
  #pragma unroll
  for (int j = 0; j < 20; ++j){
    float zn = (z[j] - mu[j]) * istd[j] * gamma[j] + beta[j];
    zn = fmaxf(zn, 0.f);
    #pragma unroll
    for (int jo = 0; jo < 10; ++jo) o[jo] = fmaf(zn, w2[j*10 + jo], o[jo]);
  }
  #pragma unroll
  for (int jo = 0; jo < 10; ++jo) out[r*10 + jo] = o[jo];
}

// ---------- launch ----------
extern "C" void kernel_launch(void* const* d_in, const int* in_sizes, int n_in,
                              void* d_out, int out_size, void* d_ws, size_t ws_size,
                              hipStream_t stream){
  const float* x      = (const float*)d_in[0];
  const int*   eidx   = (const int*)d_in[1];
  const float* w_root = (const float*)d_in[4];
  const float* w_rel  = (const float*)d_in[5];
  const float* b_conv = (const float*)d_in[6];
  const float* down_w = (const float*)d_in[7];
  const float* w1     = (const float*)d_in[8];
  const float* b1     = (const float*)d_in[9];
  const float* gamma  = (const float*)d_in[10];
  const float* beta   = (const float*)d_in[11];
  const float* w2     = (const float*)d_in[12];
  const float* b2     = (const float*)d_in[13];
  const int* src = eidx;
  const int* dst = eidx + EE;

  char* wsp = (char*)d_ws;
  size_t off = 0;
  auto alloc = [&](size_t bytes)->char*{
    char* p = wsp + off;
    off += (bytes + 255) & ~(size_t)255;
    return p;
  };
  unsigned short* hb   = (unsigned short*)alloc((size_t)NN*HH*2);   // bf16 h (in-place)
  unsigned short* aggb = (unsigned short*)alloc((size_t)NN*HH*2);   // bf16 agg
  unsigned short* wtb  = (unsigned short*)alloc((size_t)6*128*128*2);
  float*    pooled = (float*)   alloc((size_t)SS*PP*4);
  int*      rowptr = (int*)     alloc((size_t)(NN+1)*4);
  int*      csr    = (int*)     alloc((size_t)EE*4);
  unsigned* bdata  = (unsigned*)alloc((size_t)256*BCAP*4);
  int*      bcur   = (int*)     alloc((size_t)256*4);
  float*    gout   = (float*)   alloc((size_t)GG*PP*4);

  hipMemsetAsync(bcur, 0, 256*4, stream);

  x2bf<<<NN*HH/8/256, 256, 0, stream>>>(x, hb);
  wt_k<<<6*128, 128, 0, stream>>>(w_rel, w_root, wtb);
  bucket1<<<EE/EPB1, 256, 0, stream>>>(src, dst, bcur, bdata);
  bucket2<<<256, 256, 0, stream>>>(bdata, bcur, rowptr, csr);

  for (int l = 0; l < LLAYERS; ++l){
    agg_bf<<<NN/4, 256, 0, stream>>>((const unsigned*)hb, rowptr, csr, (unsigned*)aggb);
    conv_mfma<<<NN/128, 256, 0, stream>>>(aggb, hb, wtb + (size_t)l*2*16384,
        b_conv + (size_t)l*HH, hb);
  }

  pool_proj<<<SS/16, 256, 0, stream>>>((const unsigned*)hb, down_w, pooled);
  graph_softmax<<<GG, 256, 0, stream>>>(pooled, gout);
  mlp_kernel<<<1, 256, 0, stream>>>(gout, w1, b1, gamma, beta, w2, b2, (float*)d_out);
}

// Round 7
// 214.169 us; speedup vs baseline: 1.3275x; 1.0186x over previous
//
#include <hip/hip_runtime.h>
#include <hip/hip_bf16.h>

#define NN 65536
#define EE 655360
#define GG 256
#define EGOC 64
#define SS (GG*EGOC)
#define HH 128
#define PP 64
#define OUTD 10
#define LLAYERS 3
#define PADW 40   // padded LDS row stride in halfwords
#define EPB1 5120 // edges per bucket1 block
#define BCAP 4096 // per-bucket capacity

typedef __attribute__((ext_vector_type(8))) short short8_t;   // 8 bf16 = 4 VGPR
typedef __attribute__((ext_vector_type(4))) float f32x4_t;

__device__ __forceinline__ unsigned short f2bf(float f){
  unsigned u = __float_as_uint(f);
  unsigned r = (u + 0x7fffu + ((u >> 16) & 1u)) >> 16;   // RNE
  return (unsigned short)r;
}
__device__ __forceinline__ float bflo(unsigned v){ return __uint_as_float(v << 16); }
__device__ __forceinline__ float bfhi(unsigned v){ return __uint_as_float(v & 0xffff0000u); }

// ---------- x (fp32) -> bf16 ; block 0 also zeroes the bucket cursors ----------
__global__ __launch_bounds__(256) void x2bf(const float* __restrict__ x,
                                            unsigned short* __restrict__ xb,
                                            int* __restrict__ bcur){
  if (blockIdx.x == 0) bcur[threadIdx.x] = 0;   // 256 ints, visible to later kernels
  const size_t i = ((size_t)blockIdx.x * 256 + threadIdx.x) * 8;
  float4 a = *(const float4*)(x + i);
  float4 b = *(const float4*)(x + i + 4);
  uint4 o;
  o.x = f2bf(a.x) | ((unsigned)f2bf(a.y) << 16);
  o.y = f2bf(a.z) | ((unsigned)f2bf(a.w) << 16);
  o.z = f2bf(b.x) | ((unsigned)f2bf(b.y) << 16);
  o.w = f2bf(b.z) | ((unsigned)f2bf(b.w) << 16);
  *(uint4*)(xb + i) = o;
}

// ---------- transpose weights to [layer][rel|root][n][k] bf16 ----------
__global__ __launch_bounds__(128) void wt_k(const float* __restrict__ w_rel,
    const float* __restrict__ w_root, unsigned short* __restrict__ wt){
  const int mi = blockIdx.x >> 7;       // 0..5 : layer*2 + (0=rel,1=root)
  const int n  = blockIdx.x & 127;
  const int k  = threadIdx.x;
  const float* src = (mi & 1) ? w_root : w_rel;
  const int l = mi >> 1;
  float v = src[(size_t)l * 16384 + (size_t)k * 128 + n];
  wt[((size_t)mi << 14) + ((size_t)n << 7) + k] = f2bf(v);
}

// ---------- bucket pass 1: multisplit edges by dst>>8 ----------
__global__ __launch_bounds__(256) void bucket1(const int* __restrict__ src,
    const int* __restrict__ dst, int* __restrict__ bucket_cursor,
    unsigned* __restrict__ bdata){
  __shared__ int hist[256], lbase[256], cur[256], rbase[256];
  __shared__ unsigned staged[EPB1];
  const int t = threadIdx.x;
  const int e0 = blockIdx.x * EPB1;
  hist[t] = 0;
  __syncthreads();
  #pragma unroll
  for (int k = 0; k < EPB1/256; ++k){
    int d = dst[e0 + t + k*256];
    atomicAdd(&hist[d >> 8], 1);
  }
  __syncthreads();
  const int cnt = hist[t];
  int val = cnt;
  for (int off = 1; off < 256; off <<= 1){
    int y = (t >= off) ? hist[t - off] : 0;
    __syncthreads();
    val += y;
    hist[t] = val;
    __syncthreads();
  }
  const int excl = val - cnt;
  lbase[t] = excl;
  cur[t] = excl;
  rbase[t] = atomicAdd(&bucket_cursor[t], cnt);
  __syncthreads();
  #pragma unroll
  for (int k = 0; k < EPB1/256; ++k){
    int i = e0 + t + k*256;
    int d = dst[i];
    int s = src[i];
    int b = d >> 8;
    int p = atomicAdd(&cur[b], 1);
    staged[p] = (unsigned)s | ((unsigned)(d & 255) << 16) | ((unsigned)b << 24);
  }
  __syncthreads();
  #pragma unroll
  for (int k = 0; k < EPB1/256; ++k){
    int i = t + k*256;
    unsigned w = staged[i];
    int b = w >> 24;
    bdata[b * BCAP + rbase[b] + (i - lbase[b])] = w;
  }
}

// ---------- bucket pass 2: per-bucket CSR finalize ----------
__global__ __launch_bounds__(256) void bucket2(const unsigned* __restrict__ bdata,
    const int* __restrict__ bucket_cursor, int* __restrict__ rowptr,
    int* __restrict__ csr){
  __shared__ int hist[256], cur[256], red[256];
  const int t = threadIdx.x;
  const int b = blockIdx.x;
  red[t] = (t < b) ? bucket_cursor[t] : 0;
  hist[t] = 0;
  __syncthreads();
  for (int off = 128; off > 0; off >>= 1){
    if (t < off) red[t] += red[t + off];
    __syncthreads();
  }
  const int base = red[0];
  const int cnt = bucket_cursor[b];
  const unsigned* bd = bdata + (size_t)b * BCAP;
  for (int i = t; i < cnt; i += 256)
    atomicAdd(&hist[(bd[i] >> 16) & 255], 1);
  __syncthreads();
  const int c = hist[t];
  int val = c;
  for (int off = 1; off < 256; off <<= 1){
    int y = (t >= off) ? hist[t - off] : 0;
    __syncthreads();
    val += y;
    hist[t] = val;
    __syncthreads();
  }
  const int excl = val - c;
  cur[t] = excl;
  rowptr[(b << 8) + t] = base + excl;
  if (b == 255 && t == 255) rowptr[NN] = EE;
  __syncthreads();
  for (int i = t; i < cnt; i += 256){
    unsigned w = bd[i];
    int dl = (w >> 16) & 255;
    int p = atomicAdd(&cur[dl], 1);
    csr[base + p] = (int)(w & 0xFFFFu);
  }
}

// ---------- aggregation on bf16 rows: aggb[i] = sum_{j->i} hb[j] ----------
// uint4 per lane: 16 lanes cover a 256B row; wave covers 4 edges per load,
// 16 edge slots per iteration -> up to 16 edges (4KB) in flight, exec-masked.
__global__ __launch_bounds__(256) void agg_bf(const unsigned* __restrict__ hb,
    const int* __restrict__ rowptr, const int* __restrict__ csr,
    unsigned* __restrict__ aggb){
  const int wid = threadIdx.x >> 6;
  const int lane = threadIdx.x & 63;
  const int node = (blockIdx.x << 2) + wid;
  const int beg = rowptr[node], end = rowptr[node + 1];
  const int sub = lane >> 4;      // edge slot 0..3
  const int c = lane & 15;        // 16 lanes x 16B cover the row
  float a0=0.f,a1=0.f,a2=0.f,a3=0.f,a4=0.f,a5=0.f,a6=0.f,a7=0.f;
  for (int j = beg; j < end; j += 16){
    #pragma unroll
    for (int u = 0; u < 4; ++u){
      const int e = j + (u << 2) + sub;
      if (e < end){
        const int s = csr[e];
        uint4 w = *(const uint4*)(hb + ((size_t)s << 6) + (c << 2));
        a0 += bflo(w.x); a1 += bfhi(w.x);
        a2 += bflo(w.y); a3 += bfhi(w.y);
        a4 += bflo(w.z); a5 += bfhi(w.z);
        a6 += bflo(w.w); a7 += bfhi(w.w);
      }
    }
  }
  a0 += __shfl_xor(a0, 16, 64); a1 += __shfl_xor(a1, 16, 64);
  a2 += __shfl_xor(a2, 16, 64); a3 += __shfl_xor(a3, 16, 64);
  a4 += __shfl_xor(a4, 16, 64); a5 += __shfl_xor(a5, 16, 64);
  a6 += __shfl_xor(a6, 16, 64); a7 += __shfl_xor(a7, 16, 64);
  a0 += __shfl_xor(a0, 32, 64); a1 += __shfl_xor(a1, 32, 64);
  a2 += __shfl_xor(a2, 32, 64); a3 += __shfl_xor(a3, 32, 64);
  a4 += __shfl_xor(a4, 32, 64); a5 += __shfl_xor(a5, 32, 64);
  a6 += __shfl_xor(a6, 32, 64); a7 += __shfl_xor(a7, 32, 64);
  if (lane < 16){
    uint4 o;
    o.x = (unsigned)f2bf(a0) | ((unsigned)f2bf(a1) << 16);
    o.y = (unsigned)f2bf(a2) | ((unsigned)f2bf(a3) << 16);
    o.z = (unsigned)f2bf(a4) | ((unsigned)f2bf(a5) << 16);
    o.w = (unsigned)f2bf(a6) | ((unsigned)f2bf(a7) << 16);
    *(uint4*)(aggb + ((size_t)node << 6) + (c << 2)) = o;
  }
}

// ---------- MFMA conv: out = relu([agg|h] @ [wrel;wroot] + b), bf16 in/out ----------
__global__ __launch_bounds__(256) void conv_mfma(
    const unsigned short* __restrict__ Aagg, const unsigned short* __restrict__ Ah,
    const unsigned short* __restrict__ wt,   // [2][128n][128k] bf16: rel then root
    const float* __restrict__ bias,
    unsigned short* __restrict__ out){
  __shared__ unsigned short As[2][128 * PADW];
  __shared__ unsigned short Ws[2][128 * PADW];
  const int tid = threadIdx.x;
  const int row0 = blockIdx.x << 7;
  const int lane = tid & 63, wid = tid >> 6;
  const int wm64 = (wid >> 1) << 6;      // m half
  const int wn64 = (wid & 1) << 6;       // n half
  const int fr = lane & 15;              // fragment row
  const int fs = (lane >> 4) << 3;       // fragment k-slot (halfwords)
  const int r0 = tid >> 2;               // staging row 0..63
  const int s8 = (tid & 3) << 3;         // staging k-slot (halfwords)

  f32x4_t acc[4][4];
  #pragma unroll
  for (int i = 0; i < 4; ++i)
    #pragma unroll
    for (int j = 0; j < 4; ++j) acc[i][j] = (f32x4_t){0.f,0.f,0.f,0.f};

  uint4 ga0, ga1, gw0, gw1;

#define STAGE_LOAD(c) do{ \
    const unsigned short* Ap = ((c) < 4) ? Aagg : Ah; \
    const unsigned short* Wp = ((c) < 4) ? wt : (wt + 16384); \
    const int k0 = ((c) & 3) << 5; \
    ga0 = *(const uint4*)(Ap + (size_t)(row0 + r0) * 128 + k0 + s8); \
    ga1 = *(const uint4*)(Ap + (size_t)(row0 + 64 + r0) * 128 + k0 + s8); \
    gw0 = *(const uint4*)(Wp + (size_t)r0 * 128 + k0 + s8); \
    gw1 = *(const uint4*)(Wp + (size_t)(64 + r0) * 128 + k0 + s8); } while(0)
#define STAGE_WRITE(b) do{ \
    *(uint4*)&As[b][r0 * PADW + s8] = ga0; \
    *(uint4*)&As[b][(64 + r0) * PADW + s8] = ga1; \
    *(uint4*)&Ws[b][r0 * PADW + s8] = gw0; \
    *(uint4*)&Ws[b][(64 + r0) * PADW + s8] = gw1; } while(0)

  STAGE_LOAD(0);
  STAGE_WRITE(0);
  __syncthreads();

  for (int c = 0; c < 8; ++c){
    const int b = c & 1;
    if (c < 7) STAGE_LOAD(c + 1);

    short8_t af[4], wf[4];
    #pragma unroll
    for (int i = 0; i < 4; ++i)
      af[i] = *(const short8_t*)&As[b][(wm64 + i*16 + fr) * PADW + fs];
    #pragma unroll
    for (int j = 0; j < 4; ++j)
      wf[j] = *(const short8_t*)&Ws[b][(wn64 + j*16 + fr) * PADW + fs];
    #pragma unroll
    for (int j = 0; j < 4; ++j)
      #pragma unroll
      for (int i = 0; i < 4; ++i)
        acc[i][j] = __builtin_amdgcn_mfma_f32_16x16x32_bf16(wf[j], af[i], acc[i][j], 0, 0, 0);

    if (c < 7){
      STAGE_WRITE(b ^ 1);
      __syncthreads();
    }
  }
#undef STAGE_LOAD
#undef STAGE_WRITE

  // D mapping: col(lane&15) = activation row m; row((lane>>4)*4+r) = weight col n
  #pragma unroll
  for (int j = 0; j < 4; ++j){
    const int n0 = wn64 + j*16 + ((lane >> 4) << 2);
    float4 b4 = *(const float4*)(bias + n0);
    #pragma unroll
    for (int i = 0; i < 4; ++i){
      const int m = row0 + wm64 + i*16 + fr;
      float v0 = fmaxf(acc[i][j][0] + b4.x, 0.f);
      float v1 = fmaxf(acc[i][j][1] + b4.y, 0.f);
      float v2 = fmaxf(acc[i][j][2] + b4.z, 0.f);
      float v3 = fmaxf(acc[i][j][3] + b4.w, 0.f);
      uint2 pk;
      pk.x = (unsigned)f2bf(v0) | ((unsigned)f2bf(v1) << 16);
      pk.y = (unsigned)f2bf(v2) | ((unsigned)f2bf(v3) << 16);
      *(uint2*)(out + (size_t)m * 128 + n0) = pk;
    }
  }
}

// ---------- pooled[s] = (sum_{i in seg s} h_i) @ down_w  (h in bf16) ----------
__global__ __launch_bounds__(256) void pool_proj(const unsigned* __restrict__ hb,
    const float* __restrict__ down_w, float* __restrict__ pooled){
  __shared__ float wds[128 * 64];   // [k][c], 32 KB
  __shared__ float hs[4][128];
  const int tid = threadIdx.x;
  for (int i = tid; i < 128 * 64 / 4; i += 256)
    ((float4*)wds)[i] = ((const float4*)down_w)[i];
  __syncthreads();
  const int wid = tid >> 6, lane = tid & 63;
  for (int it = 0; it < 4; ++it){
    const int s = (blockIdx.x << 4) + (it << 2) + wid;
    const int b = s >> 6, e = s & 63;
    const unsigned* hr = hb + (((size_t)(b * 256 + e)) << 6) + lane;
    float ax = 0.f, ay = 0.f;
    #pragma unroll
    for (int q = 0; q < 4; ++q){
      unsigned v = hr[(size_t)q * 64 * 64];
      ax += bflo(v); ay += bfhi(v);
    }
    hs[wid][(lane << 1) + 0] = ax;
    hs[wid][(lane << 1) + 1] = ay;
    float a0 = 0.f, a1 = 0.f, a2 = 0.f, a3 = 0.f;
    #pragma unroll
    for (int k = 0; k < 128; k += 4){
      a0 = fmaf(hs[wid][k + 0], wds[(k + 0) * 64 + lane], a0);
      a1 = fmaf(hs[wid][k + 1], wds[(k + 1) * 64 + lane], a1);
      a2 = fmaf(hs[wid][k + 2], wds[(k + 2) * 64 + lane], a2);
      a3 = fmaf(hs[wid][k + 3], wds[(k + 3) * 64 + lane], a3);
    }
    pooled[(size_t)s * 64 + lane] = (a0 + a1) + (a2 + a3);
  }
}

// ---------- per-graph softmax aggregation ----------
__global__ __launch_bounds__(256) void graph_softmax(const float* __restrict__ pooled,
    float* __restrict__ gout){
  __shared__ float ps[4096];
  __shared__ float r1[4][64], r2[4][64];
  const int tid = threadIdx.x;
  const float* P = pooled + (size_t)blockIdx.x * 4096;
  for (int i = tid; i < 1024; i += 256)
    ((float4*)ps)[i] = ((const float4*)P)[i];
  __syncthreads();
  const int wid = tid >> 6, lane = tid & 63;
  float m = -3.4e38f;
  #pragma unroll
  for (int r = 0; r < 16; ++r) m = fmaxf(m, ps[((wid << 4) + r) * 64 + lane]);
  r1[wid][lane] = m;
  __syncthreads();
  m = fmaxf(fmaxf(r1[0][lane], r1[1][lane]), fmaxf(r1[2][lane], r1[3][lane]));
  __syncthreads();
  float se = 0.f, sn = 0.f;
  #pragma unroll
  for (int r = 0; r < 16; ++r){
    float p = ps[((wid << 4) + r) * 64 + lane];
    float ev = expf(p - m);
    se += ev; sn += ev * p;
  }
  r1[wid][lane] = se; r2[wid][lane] = sn;
  __syncthreads();
  if (wid == 0){
    float d = (r1[0][lane] + r1[1][lane]) + (r1[2][lane] + r1[3][lane]);
    float n = (r2[0][lane] + r2[1][lane]) + (r2[2][lane] + r2[3][lane]);
    gout[(size_t)blockIdx.x * 64 + lane] = n / d;
  }
}

// ---------- MLP ----------
__global__ __launch_bounds__(256) void mlp_kernel(const float* __restrict__ gmat,
    const float* __restrict__ w1, const float* __restrict__ b1,
    const float* __restrict__ gamma, const float* __restrict__ beta,
    const float* __restrict__ w2, const float* __restrict__ b2,
    float* __restrict__ out){
  const int r = threadIdx.x;
  float z[20];
  #pragma unroll
  for (int j = 0; j < 20; ++j) z[j] = b1[j];
  for (int k = 0; k < 64; ++k){
    float gv = gmat[r*64 + k];
    #pragma unroll
    for (int j = 0; j < 20; ++j) z[j] = fmaf(gv, w1[k*20 + j], z[j]);
  }
  __shared__ float red1[4][20], red2[4][20];
  __shared__ float mu[20], istd[20];
  const int lane = r & 63, wid = r >> 6;
  #pragma unroll
  for (int j = 0; j < 20; ++j){
    float a = z[j], b = z[j]*z[j];
    #pragma unroll
    for (int off = 32; off > 0; off >>= 1){
      a += __shfl_xor(a, off, 64);
      b += __shfl_xor(b, off, 64);
    }
    if (lane == 0){ red1[wid][j] = a; red2[wid][j] = b; }
  }
  __syncthreads();
  if (r < 20){
    float m = red1[0][r] + red1[1][r] + red1[2][r] + red1[3][r];
    float q = red2[0][r] + red2[1][r] + red2[2][r] + red2[3][r];
    m *= (1.f/256.f); q *= (1.f/256.f);
    float var = q - m*m;
    mu[r] = m;
    istd[r] = 1.f / sqrtf(var + 1e-5f);
  }
  __syncthreads();
  float o[10];
  #pragma unroll
  for (int jo = 0; jo < 10; ++jo) o[jo] = b2[jo];
  #pragma unroll
  for (int j = 0; j < 20; ++j){
    float zn = (z[j] - mu[j]) * istd[j] * gamma[j] + beta[j];
    zn = fmaxf(zn, 0.f);
    #pragma unroll
    for (int jo = 0; jo < 10; ++jo) o[jo] = fmaf(zn, w2[j*10 + jo], o[jo]);
  }
  #pragma unroll
  for (int jo = 0; jo < 10; ++jo) out[r*10 + jo] = o[jo];
}

// ---------- launch ----------
extern "C" void kernel_launch(void* const* d_in, const int* in_sizes, int n_in,
                              void* d_out, int out_size, void* d_ws, size_t ws_size,
                              hipStream_t stream){
  const float* x      = (const float*)d_in[0];
  const int*   eidx   = (const int*)d_in[1];
  const float* w_root = (const float*)d_in[4];
  const float* w_rel  = (const float*)d_in[5];
  const float* b_conv = (const float*)d_in[6];
  const float* down_w = (const float*)d_in[7];
  const float* w1     = (const float*)d_in[8];
  const float* b1     = (const float*)d_in[9];
  const float* gamma  = (const float*)d_in[10];
  const float* beta   = (const float*)d_in[11];
  const float* w2     = (const float*)d_in[12];
  const float* b2     = (const float*)d_in[13];
  const int* src = eidx;
  const int* dst = eidx + EE;

  char* wsp = (char*)d_ws;
  size_t off = 0;
  auto alloc = [&](size_t bytes)->char*{
    char* p = wsp + off;
    off += (bytes + 255) & ~(size_t)255;
    return p;
  };
  unsigned short* hb   = (unsigned short*)alloc((size_t)NN*HH*2);   // bf16 h (in-place)
  unsigned short* aggb = (unsigned short*)alloc((size_t)NN*HH*2);   // bf16 agg
  unsigned short* wtb  = (unsigned short*)alloc((size_t)6*128*128*2);
  float*    pooled = (float*)   alloc((size_t)SS*PP*4);
  int*      rowptr = (int*)     alloc((size_t)(NN+1)*4);
  int*      csr    = (int*)     alloc((size_t)EE*4);
  unsigned* bdata  = (unsigned*)alloc((size_t)256*BCAP*4);
  int*      bcur   = (int*)     alloc((size_t)256*4);
  float*    gout   = (float*)   alloc((size_t)GG*PP*4);

  x2bf<<<NN*HH/8/256, 256, 0, stream>>>(x, hb, bcur);
  wt_k<<<6*128, 128, 0, stream>>>(w_rel, w_root, wtb);
  bucket1<<<EE/EPB1, 256, 0, stream>>>(src, dst, bcur, bdata);
  bucket2<<<256, 256, 0, stream>>>(bdata, bcur, rowptr, csr);

  for (int l = 0; l < LLAYERS; ++l){
    agg_bf<<<NN/4, 256, 0, stream>>>((const unsigned*)hb, rowptr, csr, (unsigned*)aggb);
    conv_mfma<<<NN/128, 256, 0, stream>>>(aggb, hb, wtb + (size_t)l*2*16384,
        b_conv + (size_t)l*HH, hb);
  }

  pool_proj<<<SS/16, 256, 0, stream>>>((const unsigned*)hb, down_w, pooled);
  graph_softmax<<<GG, 256, 0, stream>>>(pooled, gout);
  mlp_kernel<<<1, 256, 0, stream>>>(gout, w1, b1, gamma, beta, w2, b2, (float*)d_out);
}

// Round 8
// 190.774 us; speedup vs baseline: 1.4903x; 1.1226x over previous
//
#include <hip/hip_runtime.h>
#include <hip/hip_bf16.h>

#define NN 65536
#define EE 655360
#define GG 256
#define EGOC 64
#define SS (GG*EGOC)
#define HH 128
#define PP 64
#define OUTD 10
#define LLAYERS 3
#define PADW 40   // padded LDS row stride in halfwords
#define EPB1 5120 // edges per bucket1 block
#define BCAP 4096 // per-bucket capacity

typedef __attribute__((ext_vector_type(8))) short short8_t;   // 8 bf16 = 4 VGPR
typedef __attribute__((ext_vector_type(4))) float f32x4_t;

__device__ __forceinline__ unsigned short f2bf(float f){
  unsigned u = __float_as_uint(f);
  unsigned r = (u + 0x7fffu + ((u >> 16) & 1u)) >> 16;   // RNE
  return (unsigned short)r;
}
__device__ __forceinline__ float bflo(unsigned v){ return __uint_as_float(v << 16); }
__device__ __forceinline__ float bfhi(unsigned v){ return __uint_as_float(v & 0xffff0000u); }

// ---------- prep: x->bf16 (blocks 0..4095), weight transpose (4096..4479), bcur zero ----------
__global__ __launch_bounds__(256) void prep(const float* __restrict__ x,
    unsigned short* __restrict__ xb, int* __restrict__ bcur,
    const float* __restrict__ w_rel, const float* __restrict__ w_root,
    unsigned short* __restrict__ wt){
  const int b = blockIdx.x;
  if (b < 4096){
    if (b == 0) bcur[threadIdx.x] = 0;
    const size_t i = ((size_t)b * 256 + threadIdx.x) * 8;
    float4 a = *(const float4*)(x + i);
    float4 v = *(const float4*)(x + i + 4);
    uint4 o;
    o.x = f2bf(a.x) | ((unsigned)f2bf(a.y) << 16);
    o.y = f2bf(a.z) | ((unsigned)f2bf(a.w) << 16);
    o.z = f2bf(v.x) | ((unsigned)f2bf(v.y) << 16);
    o.w = f2bf(v.z) | ((unsigned)f2bf(v.w) << 16);
    *(uint4*)(xb + i) = o;
  } else {
    const int idx = (b - 4096) * 256 + threadIdx.x;   // < 6*128*128
    const int mi = idx >> 14;            // layer*2 + (0=rel,1=root)
    const int n = (idx >> 7) & 127, k = idx & 127;
    const float* src = (mi & 1) ? w_root : w_rel;
    const int l = mi >> 1;
    wt[idx] = f2bf(src[(size_t)l * 16384 + (size_t)k * 128 + n]);
  }
}

// ---------- bucket pass 1: multisplit edges by dst>>8 ----------
__global__ __launch_bounds__(256) void bucket1(const int* __restrict__ src,
    const int* __restrict__ dst, int* __restrict__ bucket_cursor,
    unsigned* __restrict__ bdata){
  __shared__ int hist[256], lbase[256], cur[256], rbase[256];
  __shared__ unsigned staged[EPB1];
  const int t = threadIdx.x;
  const int e0 = blockIdx.x * EPB1;
  hist[t] = 0;
  __syncthreads();
  #pragma unroll
  for (int k = 0; k < EPB1/256; ++k){
    int d = dst[e0 + t + k*256];
    atomicAdd(&hist[d >> 8], 1);
  }
  __syncthreads();
  const int cnt = hist[t];
  int val = cnt;
  for (int off = 1; off < 256; off <<= 1){
    int y = (t >= off) ? hist[t - off] : 0;
    __syncthreads();
    val += y;
    hist[t] = val;
    __syncthreads();
  }
  const int excl = val - cnt;
  lbase[t] = excl;
  cur[t] = excl;
  rbase[t] = atomicAdd(&bucket_cursor[t], cnt);
  __syncthreads();
  #pragma unroll
  for (int k = 0; k < EPB1/256; ++k){
    int i = e0 + t + k*256;
    int d = dst[i];
    int s = src[i];
    int b = d >> 8;
    int p = atomicAdd(&cur[b], 1);
    staged[p] = (unsigned)s | ((unsigned)(d & 255) << 16) | ((unsigned)b << 24);
  }
  __syncthreads();
  #pragma unroll
  for (int k = 0; k < EPB1/256; ++k){
    int i = t + k*256;
    unsigned w = staged[i];
    int b = w >> 24;
    bdata[b * BCAP + rbase[b] + (i - lbase[b])] = w;
  }
}

// ---------- bucket pass 2: per-bucket CSR finalize ----------
__global__ __launch_bounds__(256) void bucket2(const unsigned* __restrict__ bdata,
    const int* __restrict__ bucket_cursor, int* __restrict__ rowptr,
    int* __restrict__ csr){
  __shared__ int hist[256], cur[256], red[256];
  const int t = threadIdx.x;
  const int b = blockIdx.x;
  red[t] = (t < b) ? bucket_cursor[t] : 0;
  hist[t] = 0;
  __syncthreads();
  for (int off = 128; off > 0; off >>= 1){
    if (t < off) red[t] += red[t + off];
    __syncthreads();
  }
  const int base = red[0];
  const int cnt = bucket_cursor[b];
  const unsigned* bd = bdata + (size_t)b * BCAP;
  for (int i = t; i < cnt; i += 256)
    atomicAdd(&hist[(bd[i] >> 16) & 255], 1);
  __syncthreads();
  const int c = hist[t];
  int val = c;
  for (int off = 1; off < 256; off <<= 1){
    int y = (t >= off) ? hist[t - off] : 0;
    __syncthreads();
    val += y;
    hist[t] = val;
    __syncthreads();
  }
  const int excl = val - c;
  cur[t] = excl;
  rowptr[(b << 8) + t] = base + excl;
  if (b == 255 && t == 255) rowptr[NN] = EE;
  __syncthreads();
  for (int i = t; i < cnt; i += 256){
    unsigned w = bd[i];
    int dl = (w >> 16) & 255;
    int p = atomicAdd(&cur[dl], 1);
    csr[base + p] = (int)(w & 0xFFFFu);
  }
}

// ---------- aggregation: grid-stride, 8 nodes/wave, software-pipelined ----------
// 8192 waves (32/CU all-resident). Per node: 16-edge window (4 uint4 gathers in
// flight), next node's rowptr prefetched under the gather, next csr window
// loaded right after the store. Tail loop covers deg>16 (rare, Poisson(10)).
__global__ __launch_bounds__(256) void agg_bf(const unsigned* __restrict__ hb,
    const int* __restrict__ rowptr, const int* __restrict__ csr,
    unsigned* __restrict__ aggb){
  const int wid = threadIdx.x >> 6;
  const int lane = threadIdx.x & 63;
  const int sub = lane >> 4;      // edge slot 0..3
  const int c = lane & 15;        // 16 lanes x 16B cover the 256B row
  int node = (blockIdx.x << 2) + wid;     // wave id 0..8191

  int beg = rowptr[node];
  int end = rowptr[node + 1];
  int sw0, sw1, sw2, sw3;
  {
    int e0 = beg + sub, e1 = beg + 4 + sub, e2 = beg + 8 + sub, e3 = beg + 12 + sub;
    sw0 = csr[e0 < end ? e0 : beg];
    sw1 = csr[e1 < end ? e1 : beg];
    sw2 = csr[e2 < end ? e2 : beg];
    sw3 = csr[e3 < end ? e3 : beg];
  }

  for (int g = 0; g < 8; ++g){
    // issue the 4 window gathers (up to 4KB in flight)
    uint4 w0 = *(const uint4*)(hb + ((size_t)sw0 << 6) + (c << 2));
    uint4 w1 = *(const uint4*)(hb + ((size_t)sw1 << 6) + (c << 2));
    uint4 w2 = *(const uint4*)(hb + ((size_t)sw2 << 6) + (c << 2));
    uint4 w3 = *(const uint4*)(hb + ((size_t)sw3 << 6) + (c << 2));
    // prefetch next node's row bounds under the gather latency
    int nbeg = 0, nend = 0;
    if (g < 7){
      nbeg = rowptr[node + 8192];
      nend = rowptr[node + 8193];
    }
    float a0=0.f,a1=0.f,a2=0.f,a3=0.f,a4=0.f,a5=0.f,a6=0.f,a7=0.f;
    if (beg + sub      < end){ a0+=bflo(w0.x); a1+=bfhi(w0.x); a2+=bflo(w0.y); a3+=bfhi(w0.y);
                               a4+=bflo(w0.z); a5+=bfhi(w0.z); a6+=bflo(w0.w); a7+=bfhi(w0.w); }
    if (beg + 4 + sub  < end){ a0+=bflo(w1.x); a1+=bfhi(w1.x); a2+=bflo(w1.y); a3+=bfhi(w1.y);
                               a4+=bflo(w1.z); a5+=bfhi(w1.z); a6+=bflo(w1.w); a7+=bfhi(w1.w); }
    if (beg + 8 + sub  < end){ a0+=bflo(w2.x); a1+=bfhi(w2.x); a2+=bflo(w2.y); a3+=bfhi(w2.y);
                               a4+=bflo(w2.z); a5+=bfhi(w2.z); a6+=bflo(w2.w); a7+=bfhi(w2.w); }
    if (beg + 12 + sub < end){ a0+=bflo(w3.x); a1+=bfhi(w3.x); a2+=bflo(w3.y); a3+=bfhi(w3.y);
                               a4+=bflo(w3.z); a5+=bfhi(w3.z); a6+=bflo(w3.w); a7+=bfhi(w3.w); }
    // rare tail: degree > 16
    for (int j = beg + 16; j < end; j += 16){
      #pragma unroll
      for (int u = 0; u < 4; ++u){
        const int e = j + (u << 2) + sub;
        if (e < end){
          const int s = csr[e];
          uint4 w = *(const uint4*)(hb + ((size_t)s << 6) + (c << 2));
          a0 += bflo(w.x); a1 += bfhi(w.x);
          a2 += bflo(w.y); a3 += bfhi(w.y);
          a4 += bflo(w.z); a5 += bfhi(w.z);
          a6 += bflo(w.w); a7 += bfhi(w.w);
        }
      }
    }
    a0 += __shfl_xor(a0, 16, 64); a1 += __shfl_xor(a1, 16, 64);
    a2 += __shfl_xor(a2, 16, 64); a3 += __shfl_xor(a3, 16, 64);
    a4 += __shfl_xor(a4, 16, 64); a5 += __shfl_xor(a5, 16, 64);
    a6 += __shfl_xor(a6, 16, 64); a7 += __shfl_xor(a7, 16, 64);
    a0 += __shfl_xor(a0, 32, 64); a1 += __shfl_xor(a1, 32, 64);
    a2 += __shfl_xor(a2, 32, 64); a3 += __shfl_xor(a3, 32, 64);
    a4 += __shfl_xor(a4, 32, 64); a5 += __shfl_xor(a5, 32, 64);
    a6 += __shfl_xor(a6, 32, 64); a7 += __shfl_xor(a7, 32, 64);
    if (lane < 16){
      uint4 o;
      o.x = (unsigned)f2bf(a0) | ((unsigned)f2bf(a1) << 16);
      o.y = (unsigned)f2bf(a2) | ((unsigned)f2bf(a3) << 16);
      o.z = (unsigned)f2bf(a4) | ((unsigned)f2bf(a5) << 16);
      o.w = (unsigned)f2bf(a6) | ((unsigned)f2bf(a7) << 16);
      *(uint4*)(aggb + ((size_t)node << 6) + (c << 2)) = o;
    }
    // set up next node's csr window (overlaps with next gather issue)
    if (g < 7){
      node += 8192;
      beg = nbeg; end = nend;
      int e0 = beg + sub, e1 = beg + 4 + sub, e2 = beg + 8 + sub, e3 = beg + 12 + sub;
      sw0 = csr[e0 < end ? e0 : beg];
      sw1 = csr[e1 < end ? e1 : beg];
      sw2 = csr[e2 < end ? e2 : beg];
      sw3 = csr[e3 < end ? e3 : beg];
    }
  }
}

// ---------- MFMA conv: out = relu([agg|h] @ [wrel;wroot] + b), bf16 in/out ----------
__global__ __launch_bounds__(256) void conv_mfma(
    const unsigned short* __restrict__ Aagg, const unsigned short* __restrict__ Ah,
    const unsigned short* __restrict__ wt,   // [2][128n][128k] bf16: rel then root
    const float* __restrict__ bias,
    unsigned short* __restrict__ out){
  __shared__ unsigned short As[2][128 * PADW];
  __shared__ unsigned short Ws[2][128 * PADW];
  const int tid = threadIdx.x;
  const int row0 = blockIdx.x << 7;
  const int lane = tid & 63, wid = tid >> 6;
  const int wm64 = (wid >> 1) << 6;      // m half
  const int wn64 = (wid & 1) << 6;       // n half
  const int fr = lane & 15;              // fragment row
  const int fs = (lane >> 4) << 3;       // fragment k-slot (halfwords)
  const int r0 = tid >> 2;               // staging row 0..63
  const int s8 = (tid & 3) << 3;         // staging k-slot (halfwords)

  f32x4_t acc[4][4];
  #pragma unroll
  for (int i = 0; i < 4; ++i)
    #pragma unroll
    for (int j = 0; j < 4; ++j) acc[i][j] = (f32x4_t){0.f,0.f,0.f,0.f};

  uint4 ga0, ga1, gw0, gw1;

#define STAGE_LOAD(c) do{ \
    const unsigned short* Ap = ((c) < 4) ? Aagg : Ah; \
    const unsigned short* Wp = ((c) < 4) ? wt : (wt + 16384); \
    const int k0 = ((c) & 3) << 5; \
    ga0 = *(const uint4*)(Ap + (size_t)(row0 + r0) * 128 + k0 + s8); \
    ga1 = *(const uint4*)(Ap + (size_t)(row0 + 64 + r0) * 128 + k0 + s8); \
    gw0 = *(const uint4*)(Wp + (size_t)r0 * 128 + k0 + s8); \
    gw1 = *(const uint4*)(Wp + (size_t)(64 + r0) * 128 + k0 + s8); } while(0)
#define STAGE_WRITE(b) do{ \
    *(uint4*)&As[b][r0 * PADW + s8] = ga0; \
    *(uint4*)&As[b][(64 + r0) * PADW + s8] = ga1; \
    *(uint4*)&Ws[b][r0 * PADW + s8] = gw0; \
    *(uint4*)&Ws[b][(64 + r0) * PADW + s8] = gw1; } while(0)

  STAGE_LOAD(0);
  STAGE_WRITE(0);
  __syncthreads();

  for (int c = 0; c < 8; ++c){
    const int b = c & 1;
    if (c < 7) STAGE_LOAD(c + 1);

    short8_t af[4], wf[4];
    #pragma unroll
    for (int i = 0; i < 4; ++i)
      af[i] = *(const short8_t*)&As[b][(wm64 + i*16 + fr) * PADW + fs];
    #pragma unroll
    for (int j = 0; j < 4; ++j)
      wf[j] = *(const short8_t*)&Ws[b][(wn64 + j*16 + fr) * PADW + fs];
    #pragma unroll
    for (int j = 0; j < 4; ++j)
      #pragma unroll
      for (int i = 0; i < 4; ++i)
        acc[i][j] = __builtin_amdgcn_mfma_f32_16x16x32_bf16(wf[j], af[i], acc[i][j], 0, 0, 0);

    if (c < 7){
      STAGE_WRITE(b ^ 1);
      __syncthreads();
    }
  }
#undef STAGE_LOAD
#undef STAGE_WRITE

  // D mapping: col(lane&15) = activation row m; row((lane>>4)*4+r) = weight col n
  #pragma unroll
  for (int j = 0; j < 4; ++j){
    const int n0 = wn64 + j*16 + ((lane >> 4) << 2);
    float4 b4 = *(const float4*)(bias + n0);
    #pragma unroll
    for (int i = 0; i < 4; ++i){
      const int m = row0 + wm64 + i*16 + fr;
      float v0 = fmaxf(acc[i][j][0] + b4.x, 0.f);
      float v1 = fmaxf(acc[i][j][1] + b4.y, 0.f);
      float v2 = fmaxf(acc[i][j][2] + b4.z, 0.f);
      float v3 = fmaxf(acc[i][j][3] + b4.w, 0.f);
      uint2 pk;
      pk.x = (unsigned)f2bf(v0) | ((unsigned)f2bf(v1) << 16);
      pk.y = (unsigned)f2bf(v2) | ((unsigned)f2bf(v3) << 16);
      *(uint2*)(out + (size_t)m * 128 + n0) = pk;
    }
  }
}

// ---------- pooled[s] = (sum_{i in seg s} h_i) @ down_w  (h in bf16) ----------
__global__ __launch_bounds__(256) void pool_proj(const unsigned* __restrict__ hb,
    const float* __restrict__ down_w, float* __restrict__ pooled){
  __shared__ float wds[128 * 64];   // [k][c], 32 KB
  __shared__ float hs[4][128];
  const int tid = threadIdx.x;
  for (int i = tid; i < 128 * 64 / 4; i += 256)
    ((float4*)wds)[i] = ((const float4*)down_w)[i];
  __syncthreads();
  const int wid = tid >> 6, lane = tid & 63;
  for (int it = 0; it < 4; ++it){
    const int s = (blockIdx.x << 4) + (it << 2) + wid;
    const int b = s >> 6, e = s & 63;
    const unsigned* hr = hb + (((size_t)(b * 256 + e)) << 6) + lane;
    float ax = 0.f, ay = 0.f;
    #pragma unroll
    for (int q = 0; q < 4; ++q){
      unsigned v = hr[(size_t)q * 64 * 64];
      ax += bflo(v); ay += bfhi(v);
    }
    hs[wid][(lane << 1) + 0] = ax;
    hs[wid][(lane << 1) + 1] = ay;
    float a0 = 0.f, a1 = 0.f, a2 = 0.f, a3 = 0.f;
    #pragma unroll
    for (int k = 0; k < 128; k += 4){
      a0 = fmaf(hs[wid][k + 0], wds[(k + 0) * 64 + lane], a0);
      a1 = fmaf(hs[wid][k + 1], wds[(k + 1) * 64 + lane], a1);
      a2 = fmaf(hs[wid][k + 2], wds[(k + 2) * 64 + lane], a2);
      a3 = fmaf(hs[wid][k + 3], wds[(k + 3) * 64 + lane], a3);
    }
    pooled[(size_t)s * 64 + lane] = (a0 + a1) + (a2 + a3);
  }
}

// ---------- per-graph softmax aggregation ----------
__global__ __launch_bounds__(256) void graph_softmax(const float* __restrict__ pooled,
    float* __restrict__ gout){
  __shared__ float ps[4096];
  __shared__ float r1[4][64], r2[4][64];
  const int tid = threadIdx.x;
  const float* P = pooled + (size_t)blockIdx.x * 4096;
  for (int i = tid; i < 1024; i += 256)
    ((float4*)ps)[i] = ((const float4*)P)[i];
  __syncthreads();
  const int wid = tid >> 6, lane = tid & 63;
  float m = -3.4e38f;
  #pragma unroll
  for (int r = 0; r < 16; ++r) m = fmaxf(m, ps[((wid << 4) + r) * 64 + lane]);
  r1[wid][lane] = m;
  __syncthreads();
  m = fmaxf(fmaxf(r1[0][lane], r1[1][lane]), fmaxf(r1[2][lane], r1[3][lane]));
  __syncthreads();
  float se = 0.f, sn = 0.f;
  #pragma unroll
  for (int r = 0; r < 16; ++r){
    float p = ps[((wid << 4) + r) * 64 + lane];
    float ev = expf(p - m);
    se += ev; sn += ev * p;
  }
  r1[wid][lane] = se; r2[wid][lane] = sn;
  __syncthreads();
  if (wid == 0){
    float d = (r1[0][lane] + r1[1][lane]) + (r1[2][lane] + r1[3][lane]);
    float n = (r2[0][lane] + r2[1][lane]) + (r2[2][lane] + r2[3][lane]);
    gout[(size_t)blockIdx.x * 64 + lane] = n / d;
  }
}

// ---------- MLP ----------
__global__ __launch_bounds__(256) void mlp_kernel(const float* __restrict__ gmat,
    const float* __restrict__ w1, const float* __restrict__ b1,
    const float* __restrict__ gamma, const float* __restrict__ beta,
    const float* __restrict__ w2, const float* __restrict__ b2,
    float* __restrict__ out){
  const int r = threadIdx.x;
  float z[20];
  #pragma unroll
  for (int j = 0; j < 20; ++j) z[j] = b1[j];
  for (int k = 0; k < 64; ++k){
    float gv = gmat[r*64 + k];
    #pragma unroll
    for (int j = 0; j < 20; ++j) z[j] = fmaf(gv, w1[k*20 + j], z[j]);
  }
  __shared__ float red1[4][20], red2[4][20];
  __shared__ float mu[20], istd[20];
  const int lane = r & 63, wid = r >> 6;
  #pragma unroll
  for (int j = 0; j < 20; ++j){
    float a = z[j], b = z[j]*z[j];
    #pragma unroll
    for (int off = 32; off > 0; off >>= 1){
      a += __shfl_xor(a, off, 64);
      b += __shfl_xor(b, off, 64);
    }
    if (lane == 0){ red1[wid][j] = a; red2[wid][j] = b; }
  }
  __syncthreads();
  if (r < 20){
    float m = red1[0][r] + red1[1][r] + red1[2][r] + red1[3][r];
    float q = red2[0][r] + red2[1][r] + red2[2][r] + red2[3][r];
    m *= (1.f/256.f); q *= (1.f/256.f);
    float var = q - m*m;
    mu[r] = m;
    istd[r] = 1.f / sqrtf(var + 1e-5f);
  }
  __syncthreads();
  float o[10];
  #pragma unroll
  for (int jo = 0; jo < 10; ++jo) o[jo] = b2[jo];
  #pragma unroll
  for (int j = 0; j < 20; ++j){
    float zn = (z[j] - mu[j]) * istd[j] * gamma[j] + beta[j];
    zn = fmaxf(zn, 0.f);
    #pragma unroll
    for (int jo = 0; jo < 10; ++jo) o[jo] = fmaf(zn, w2[j*10 + jo], o[jo]);
  }
  #pragma unroll
  for (int jo = 0; jo < 10; ++jo) out[r*10 + jo] = o[jo];
}

// ---------- launch ----------
extern "C" void kernel_launch(void* const* d_in, const int* in_sizes, int n_in,
                              void* d_out, int out_size, void* d_ws, size_t ws_size,
                              hipStream_t stream){
  const float* x      = (const float*)d_in[0];
  const int*   eidx   = (const int*)d_in[1];
  const float* w_root = (const float*)d_in[4];
  const float* w_rel  = (const float*)d_in[5];
  const float* b_conv = (const float*)d_in[6];
  const float* down_w = (const float*)d_in[7];
  const float* w1     = (const float*)d_in[8];
  const float* b1     = (const float*)d_in[9];
  const float* gamma  = (const float*)d_in[10];
  const float* beta   = (const float*)d_in[11];
  const float* w2     = (const float*)d_in[12];
  const float* b2     = (const float*)d_in[13];
  const int* src = eidx;
  const int* dst = eidx + EE;

  char* wsp = (char*)d_ws;
  size_t off = 0;
  auto alloc = [&](size_t bytes)->char*{
    char* p = wsp + off;
    off += (bytes + 255) & ~(size_t)255;
    return p;
  };
  unsigned short* hb   = (unsigned short*)alloc((size_t)NN*HH*2);   // bf16 h (in-place)
  unsigned short* aggb = (unsigned short*)alloc((size_t)NN*HH*2);   // bf16 agg
  unsigned short* wtb  = (unsigned short*)alloc((size_t)6*128*128*2);
  float*    pooled = (float*)   alloc((size_t)SS*PP*4);
  int*      rowptr = (int*)     alloc((size_t)(NN+1)*4);
  int*      csr    = (int*)     alloc((size_t)EE*4);
  unsigned* bdata  = (unsigned*)alloc((size_t)256*BCAP*4);
  int*      bcur   = (int*)     alloc((size_t)256*4);
  float*    gout   = (float*)   alloc((size_t)GG*PP*4);

  prep<<<4096 + 384, 256, 0, stream>>>(x, hb, bcur, w_rel, w_root, wtb);
  bucket1<<<EE/EPB1, 256, 0, stream>>>(src, dst, bcur, bdata);
  bucket2<<<256, 256, 0, stream>>>(bdata, bcur, rowptr, csr);

  for (int l = 0; l < LLAYERS; ++l){
    agg_bf<<<2048, 256, 0, stream>>>((const unsigned*)hb, rowptr, csr, (unsigned*)aggb);
    conv_mfma<<<NN/128, 256, 0, stream>>>(aggb, hb, wtb + (size_t)l*2*16384,
        b_conv + (size_t)l*HH, hb);
  }

  pool_proj<<<SS/16, 256, 0, stream>>>((const unsigned*)hb, down_w, pooled);
  graph_softmax<<<GG, 256, 0, stream>>>(pooled, gout);
  mlp_kernel<<<1, 256, 0, stream>>>(gout, w1, b1, gamma, beta, w2, b2, (float*)d_out);
}